// Round 5
// baseline (122.146 us; speedup 1.0000x reference)
//
#include <hip/hip_runtime.h>

#define BB 8
#define AA 65536
#define CC 80
#define NN 64
#define GX (AA / 256)          // 256 blocks in x
#define NBLK (BB * GX)         // 2048 total blocks
#define CHUNKS 20              // float4s per thread (256*80/4/256)
#define PF 6                   // prefetched chunks issued before phase 1
#define CANARY 0x5CA1AB1Eu

__global__ __launch_bounds__(256) void focal_fused(
    const float* __restrict__ cls,
    const float* __restrict__ anchors,
    const float* __restrict__ ann,
    unsigned long long* __restrict__ slots,   // 2 words per block: [val|CANARY],[np|CANARY]
    float* __restrict__ out)
{
    __shared__ float4 boxes[NN];     // (b0, b1, len, label)
    __shared__ float  kkArr[256];    // 0 (ignore) or -0.75*ln2
    __shared__ int    labArr[256];   // pos: label 0..79, else -1000
    __shared__ float  waveSums[4];
    __shared__ int    wavePos[4];
    __shared__ float  wS[4][BB];     // finalize scratch
    __shared__ int    wN[4][BB];

    const int tid  = threadIdx.x;
    const int b    = blockIdx.y;
    const int a0   = blockIdx.x * 256;
    const int bIdx = b * GX + blockIdx.x;

    // tiny loads first, then deep prefetch: the LDS box-staging wait leaves
    // the 6 cls prefetches in flight across phase 1.
    float g0 = 0.f, g1 = 0.f, lbf = 0.f;
    if (tid < NN) {
        g0  = ann[(b * NN + tid) * 3 + 0];
        g1  = ann[(b * NN + tid) * 3 + 1];
        lbf = ann[(b * NN + tid) * 3 + 2];
    }
    const float2 av = reinterpret_cast<const float2*>(anchors)[a0 + tid];

    const float4* base = reinterpret_cast<const float4*>(
        cls + ((size_t)b * AA + (size_t)a0) * (size_t)CC);
    float4 pr0 = base[0 * 256 + tid];
    float4 pr1 = base[1 * 256 + tid];
    float4 pr2 = base[2 * 256 + tid];
    float4 pr3 = base[3 * 256 + tid];
    float4 pr4 = base[4 * 256 + tid];
    float4 pr5 = base[5 * 256 + tid];

    if (tid < NN) boxes[tid] = make_float4(g0, g1, g1 - g0, lbf);
    __syncthreads();

    // ---- phase 1: per-anchor assignment (overlaps in-flight prefetch) ----
    const float A0 = av.x, A1 = av.y;
    const float alen = A1 - A0;
    float best = -1.0f;
    int bestn = 0;
    #pragma unroll 8
    for (int n = 0; n < NN; ++n) {
        float4 bx = boxes[n];
        float iw = fmaxf(fminf(A1, bx.y) - fmaxf(A0, bx.x), 0.0f);
        float ua = fmaxf(alen + bx.z - iw, 1e-8f);
        float iou = iw * __builtin_amdgcn_rcpf(ua);
        if (iou > best) { best = iou; bestn = n; }   // strict >: first max
    }
    const bool pos = (best >= 0.5f);
    const bool ign = (!pos) && (best >= 0.4f);
    kkArr[tid]  = ign ? 0.0f : -0.75f * 0.69314718056f;  // kk * p^2 * log2(q)
    labArr[tid] = pos ? (int)boxes[bestn].w : -1000;

    unsigned long long bal = __ballot(pos);
    const int lane = tid & 63;
    const int wid  = tid >> 6;
    if (lane == 0) wavePos[wid] = __popcll(bal);
    __syncthreads();

    // ---- phase 2: stream; uniform negative term + rare one-hot fix ----
    float acc = 0.0f;

#define PROC(I, V) {                                                        \
        int idx = (I) * 256 + tid;                                          \
        int al  = idx / CHUNKS;                                             \
        int c0  = (idx - al * CHUNKS) * 4;                                  \
        float kk = kkArr[al];                                               \
        int  lab = labArr[al];                                              \
        float p0 = (V).x, p1 = (V).y, p2 = (V).z, p3 = (V).w;               \
        float s0 = p0 * p0 * __log2f(1.0f - p0);                            \
        float s1 = p1 * p1 * __log2f(1.0f - p1);                            \
        float s2 = p2 * p2 * __log2f(1.0f - p2);                            \
        float s3 = p3 * p3 * __log2f(1.0f - p3);                            \
        acc += kk * ((s0 + s1) + (s2 + s3));                                \
        if ((unsigned)(lab - c0) < 4u) {                                    \
            int j = lab - c0;                                               \
            float p = (j == 0) ? p0 : (j == 1) ? p1 : (j == 2) ? p2 : p3;   \
            float q = 1.0f - p;                                             \
            acc += 0.69314718056f * (0.75f * p * p * __log2f(q)             \
                                   - 0.25f * q * q * __log2f(p));           \
        }                                                                   \
    }

    PROC(0, pr0) PROC(1, pr1) PROC(2, pr2)
    PROC(3, pr3) PROC(4, pr4) PROC(5, pr5)

    // 2-deep software pipeline over the remaining 14 chunks (6..19)
    {
        float4 c0v = base[PF * 256 + tid];
        float4 c1v = base[(PF + 1) * 256 + tid];
        #pragma unroll
        for (int i = PF; i < CHUNKS - 2; i += 2) {
            float4 n0 = base[(i + 2) * 256 + tid];
            float4 n1 = base[(i + 3) * 256 + tid];
            PROC(i, c0v)
            PROC(i + 1, c1v)
            c0v = n0; c1v = n1;
        }
        PROC(CHUNKS - 2, c0v)
        PROC(CHUNKS - 1, c1v)
    }
#undef PROC

    // ---- block reduction -> canary-tagged slot publish ----
    #pragma unroll
    for (int off = 32; off > 0; off >>= 1)
        acc += __shfl_down(acc, off, 64);
    if (lane == 0) waveSums[wid] = acc;
    __syncthreads();

    if (tid == 0) {
        float bs = waveSums[0] + waveSums[1] + waveSums[2] + waveSums[3];
        int   np = wavePos[0] + wavePos[1] + wavePos[2] + wavePos[3];
        unsigned long long w0 =
            ((unsigned long long)__float_as_uint(bs) << 32) | CANARY;
        unsigned long long w1 =
            ((unsigned long long)(unsigned int)np << 32) | CANARY;
        __hip_atomic_store(&slots[2 * bIdx],     w0,
                           __ATOMIC_RELEASE, __HIP_MEMORY_SCOPE_AGENT);
        __hip_atomic_store(&slots[2 * bIdx + 1], w1,
                           __ATOMIC_RELEASE, __HIP_MEMORY_SCOPE_AGENT);
    }

    // ---- fixed finalize block: spin until all slots published, reduce ----
    if (bIdx == NBLK - 1) {
        float sv[BB];
        int   nv[BB];
        #pragma unroll
        for (int k = 0; k < BB; ++k) {
            int slot = k * GX + tid;        // sample k, entry tid (GX==256)
            unsigned long long w0, w1;
            do {
                w0 = __hip_atomic_load(&slots[2 * slot],
                                       __ATOMIC_ACQUIRE, __HIP_MEMORY_SCOPE_AGENT);
            } while ((unsigned int)w0 != CANARY);
            do {
                w1 = __hip_atomic_load(&slots[2 * slot + 1],
                                       __ATOMIC_ACQUIRE, __HIP_MEMORY_SCOPE_AGENT);
            } while ((unsigned int)w1 != CANARY);
            sv[k] = __uint_as_float((unsigned int)(w0 >> 32));
            nv[k] = (int)(unsigned int)(w1 >> 32);
        }
        #pragma unroll
        for (int k = 0; k < BB; ++k) {
            #pragma unroll
            for (int off = 32; off > 0; off >>= 1) {
                sv[k] += __shfl_down(sv[k], off, 64);
                nv[k] += __shfl_down(nv[k], off, 64);
            }
        }
        if (lane == 0) {
            #pragma unroll
            for (int k = 0; k < BB; ++k) { wS[wid][k] = sv[k]; wN[wid][k] = nv[k]; }
        }
        __syncthreads();
        if (tid == 0) {
            float m = 0.0f;
            #pragma unroll
            for (int k = 0; k < BB; ++k) {
                float s = wS[0][k] + wS[1][k] + wS[2][k] + wS[3][k];
                int  np = wN[0][k] + wN[1][k] + wN[2][k] + wN[3][k];
                m += s / fmaxf((float)np, 1.0f);
            }
            out[0] = m * (1.0f / BB);
        }
    }
}

extern "C" void kernel_launch(void* const* d_in, const int* in_sizes, int n_in,
                              void* d_out, int out_size, void* d_ws, size_t ws_size,
                              hipStream_t stream) {
    const float* cls     = (const float*)d_in[0];
    const float* anchors = (const float*)d_in[1];
    const float* ann     = (const float*)d_in[2];
    float* out = (float*)d_out;

    unsigned long long* slots = (unsigned long long*)d_ws;   // 2048*2*8 = 32 KB

    dim3 grid(GX, BB);
    focal_fused<<<grid, 256, 0, stream>>>(cls, anchors, ann, slots, out);
}

// Round 6
// 33.145 us; speedup vs baseline: 3.6852x; 3.6852x over previous
//
#include <hip/hip_runtime.h>

#define BB 8
#define AA 65536
#define CC 80
#define NN 64
#define GX (AA / 256)          // 256 blocks in x
#define CHUNKS 20              // float4s per thread (256*80/4/256)
#define PF 8                   // prefetched chunks issued before phase 1

__global__ __launch_bounds__(256) void focal_main(
    const float* __restrict__ cls,
    const float* __restrict__ anchors,
    const float* __restrict__ ann,
    float* __restrict__ partial,
    int* __restrict__ posCnt)
{
    __shared__ float4 boxes[NN];     // (b0, b1, len, label)
    __shared__ float  kkArr[256];    // 0 (ignore) or -0.75*ln2
    __shared__ int    labArr[256];   // pos: label 0..79, else -1000
    __shared__ float  waveSums[4];
    __shared__ int    wavePos[4];

    const int tid  = threadIdx.x;
    const int b    = blockIdx.y;
    const int a0   = blockIdx.x * 256;
    const int bIdx = b * GX + blockIdx.x;

    // tiny loads first, then deep prefetch: the LDS box-staging wait leaves
    // the 8 cls prefetches in flight across phase 1.
    float g0 = 0.f, g1 = 0.f, lbf = 0.f;
    if (tid < NN) {
        g0  = ann[(b * NN + tid) * 3 + 0];
        g1  = ann[(b * NN + tid) * 3 + 1];
        lbf = ann[(b * NN + tid) * 3 + 2];
    }
    const float2 av = reinterpret_cast<const float2*>(anchors)[a0 + tid];

    const float4* base = reinterpret_cast<const float4*>(
        cls + ((size_t)b * AA + (size_t)a0) * (size_t)CC);
    float4 pr0 = base[0 * 256 + tid];
    float4 pr1 = base[1 * 256 + tid];
    float4 pr2 = base[2 * 256 + tid];
    float4 pr3 = base[3 * 256 + tid];
    float4 pr4 = base[4 * 256 + tid];
    float4 pr5 = base[5 * 256 + tid];
    float4 pr6 = base[6 * 256 + tid];
    float4 pr7 = base[7 * 256 + tid];

    if (tid < NN) boxes[tid] = make_float4(g0, g1, g1 - g0, lbf);
    __syncthreads();

    // ---- phase 1: per-anchor assignment (overlaps in-flight prefetch) ----
    const float A0 = av.x, A1 = av.y;
    const float alen = A1 - A0;
    float best = -1.0f;
    int bestn = 0;
    #pragma unroll 8
    for (int n = 0; n < NN; ++n) {
        float4 bx = boxes[n];
        float iw = fmaxf(fminf(A1, bx.y) - fmaxf(A0, bx.x), 0.0f);
        float ua = fmaxf(alen + bx.z - iw, 1e-8f);
        float iou = iw * __builtin_amdgcn_rcpf(ua);
        if (iou > best) { best = iou; bestn = n; }   // strict >: first max
    }
    const bool pos = (best >= 0.5f);
    const bool ign = (!pos) && (best >= 0.4f);
    kkArr[tid]  = ign ? 0.0f : -0.75f * 0.69314718056f;  // kk * p^2 * log2(q)
    labArr[tid] = pos ? (int)boxes[bestn].w : -1000;

    unsigned long long bal = __ballot(pos);
    const int lane = tid & 63;
    const int wid  = tid >> 6;
    if (lane == 0) wavePos[wid] = __popcll(bal);
    __syncthreads();

    // ---- phase 2: stream; uniform negative term + rare one-hot fix ----
    float acc = 0.0f;

#define PROC(I, V) {                                                        \
        int idx = (I) * 256 + tid;                                          \
        int al  = idx / CHUNKS;                                             \
        int c0  = (idx - al * CHUNKS) * 4;                                  \
        float kk = kkArr[al];                                               \
        int  lab = labArr[al];                                              \
        float p0 = (V).x, p1 = (V).y, p2 = (V).z, p3 = (V).w;               \
        float s0 = p0 * p0 * __log2f(1.0f - p0);                            \
        float s1 = p1 * p1 * __log2f(1.0f - p1);                            \
        float s2 = p2 * p2 * __log2f(1.0f - p2);                            \
        float s3 = p3 * p3 * __log2f(1.0f - p3);                            \
        acc += kk * ((s0 + s1) + (s2 + s3));                                \
        if ((unsigned)(lab - c0) < 4u) {                                    \
            int j = lab - c0;                                               \
            float p = (j == 0) ? p0 : (j == 1) ? p1 : (j == 2) ? p2 : p3;   \
            float q = 1.0f - p;                                             \
            acc += 0.69314718056f * (0.75f * p * p * __log2f(q)             \
                                   - 0.25f * q * q * __log2f(p));           \
        }                                                                   \
    }

    PROC(0, pr0) PROC(1, pr1) PROC(2, pr2) PROC(3, pr3)
    PROC(4, pr4) PROC(5, pr5) PROC(6, pr6) PROC(7, pr7)

    // 2-deep software pipeline over the remaining 12 chunks (8..19)
    {
        float4 c0v = base[PF * 256 + tid];
        float4 c1v = base[(PF + 1) * 256 + tid];
        #pragma unroll
        for (int i = PF; i < CHUNKS - 2; i += 2) {
            float4 n0 = base[(i + 2) * 256 + tid];
            float4 n1 = base[(i + 3) * 256 + tid];
            PROC(i, c0v)
            PROC(i + 1, c1v)
            c0v = n0; c1v = n1;
        }
        PROC(CHUNKS - 2, c0v)
        PROC(CHUNKS - 1, c1v)
    }
#undef PROC

    // ---- block reduction -> per-block slot (no atomics, no memset) ----
    #pragma unroll
    for (int off = 32; off > 0; off >>= 1)
        acc += __shfl_down(acc, off, 64);
    if (lane == 0) waveSums[wid] = acc;
    __syncthreads();
    if (tid == 0) {
        partial[bIdx] = waveSums[0] + waveSums[1] + waveSums[2] + waveSums[3];
        posCnt[bIdx]  = wavePos[0] + wavePos[1] + wavePos[2] + wavePos[3];
    }
}

__global__ __launch_bounds__(512) void focal_final(
    const float* __restrict__ partial,
    const int* __restrict__ posCnt,
    float* __restrict__ out)
{
    __shared__ float lossS[8];
    const int tid  = threadIdx.x;
    const int w    = tid >> 6;     // wave w handles sample b = w
    const int lane = tid & 63;

    float s = 0.0f;
    int   np = 0;
    #pragma unroll
    for (int k = 0; k < 4; ++k) {
        int i = w * 256 + lane + 64 * k;
        s  += partial[i];
        np += posCnt[i];
    }
    #pragma unroll
    for (int off = 32; off > 0; off >>= 1) {
        s  += __shfl_down(s, off, 64);
        np += __shfl_down(np, off, 64);
    }
    if (lane == 0) lossS[w] = s / fmaxf((float)np, 1.0f);
    __syncthreads();
    if (tid == 0) {
        float m = 0.0f;
        #pragma unroll
        for (int bb = 0; bb < BB; ++bb) m += lossS[bb];
        out[0] = m * (1.0f / BB);
    }
}

extern "C" void kernel_launch(void* const* d_in, const int* in_sizes, int n_in,
                              void* d_out, int out_size, void* d_ws, size_t ws_size,
                              hipStream_t stream) {
    const float* cls     = (const float*)d_in[0];
    const float* anchors = (const float*)d_in[1];
    const float* ann     = (const float*)d_in[2];
    float* out = (float*)d_out;

    float* partial = (float*)d_ws;                               // 2048 floats
    int*   posCnt  = (int*)((char*)d_ws + 2048 * sizeof(float)); // 2048 ints

    dim3 grid(GX, BB);
    focal_main<<<grid, 256, 0, stream>>>(cls, anchors, ann, partial, posCnt);
    focal_final<<<1, 512, 0, stream>>>(partial, posCnt, out);
}

// Round 8
// 32.970 us; speedup vs baseline: 3.7047x; 1.0053x over previous
//
#include <hip/hip_runtime.h>

#define BB 8
#define AA 65536
#define CC 80
#define NN 64
#define GX (AA / 256)          // 256 blocks in x
#define CHUNKS 20              // float4s per thread (256*80/4/256)
#define PF 10                  // prefetched chunks issued before phase 1

__global__ __launch_bounds__(256) void focal_main(
    const float* __restrict__ cls,
    const float* __restrict__ anchors,
    const float* __restrict__ ann,
    float* __restrict__ partial,
    int* __restrict__ posCnt)
{
    __shared__ float4 boxes[NN];     // (b0, b1, len, label)
    __shared__ float  kkArr[256];    // 0 (ignore) or -0.75*ln2
    __shared__ int    labArr[256];   // pos: label 0..79, else -1000
    __shared__ float  waveSums[4];
    __shared__ int    wavePos[4];

    const int tid  = threadIdx.x;
    const int b    = blockIdx.y;
    const int a0   = blockIdx.x * 256;
    const int bIdx = b * GX + blockIdx.x;

    // tiny loads first, then deep prefetch: the LDS box-staging wait leaves
    // the 10 cls prefetches in flight across phase 1.
    float g0 = 0.f, g1 = 0.f, lbf = 0.f;
    if (tid < NN) {
        g0  = ann[(b * NN + tid) * 3 + 0];
        g1  = ann[(b * NN + tid) * 3 + 1];
        lbf = ann[(b * NN + tid) * 3 + 2];
    }
    const float2 av = reinterpret_cast<const float2*>(anchors)[a0 + tid];

    const float4* base = reinterpret_cast<const float4*>(
        cls + ((size_t)b * AA + (size_t)a0) * (size_t)CC);
    float4 pr0 = base[0 * 256 + tid];
    float4 pr1 = base[1 * 256 + tid];
    float4 pr2 = base[2 * 256 + tid];
    float4 pr3 = base[3 * 256 + tid];
    float4 pr4 = base[4 * 256 + tid];
    float4 pr5 = base[5 * 256 + tid];
    float4 pr6 = base[6 * 256 + tid];
    float4 pr7 = base[7 * 256 + tid];
    float4 pr8 = base[8 * 256 + tid];
    float4 pr9 = base[9 * 256 + tid];

    if (tid < NN) boxes[tid] = make_float4(g0, g1, g1 - g0, lbf);
    __syncthreads();

    // ---- phase 1: per-anchor assignment (overlaps in-flight prefetch) ----
    const float A0 = av.x, A1 = av.y;
    const float alen = A1 - A0;
    float best = -1.0f;
    int bestn = 0;
    #pragma unroll 8
    for (int n = 0; n < NN; ++n) {
        float4 bx = boxes[n];
        float iw = fmaxf(fminf(A1, bx.y) - fmaxf(A0, bx.x), 0.0f);
        float ua = fmaxf(alen + bx.z - iw, 1e-8f);
        float iou = iw * __builtin_amdgcn_rcpf(ua);
        if (iou > best) { best = iou; bestn = n; }   // strict >: first max
    }
    const bool pos = (best >= 0.5f);
    const bool ign = (!pos) && (best >= 0.4f);
    kkArr[tid]  = ign ? 0.0f : -0.75f * 0.69314718056f;  // kk * p^2 * log2(q)
    labArr[tid] = pos ? (int)boxes[bestn].w : -1000;

    unsigned long long bal = __ballot(pos);
    const int lane = tid & 63;
    const int wid  = tid >> 6;
    if (lane == 0) wavePos[wid] = __popcll(bal);
    __syncthreads();

    // ---- phase 2: stream; uniform negative term + rare one-hot fix ----
    float acc = 0.0f;

#define PROC(I, V) {                                                        \
        int idx = (I) * 256 + tid;                                          \
        int al  = idx / CHUNKS;                                             \
        int c0  = (idx - al * CHUNKS) * 4;                                  \
        float kk = kkArr[al];                                               \
        int  lab = labArr[al];                                              \
        float p0 = (V).x, p1 = (V).y, p2 = (V).z, p3 = (V).w;               \
        float s0 = p0 * p0 * __log2f(1.0f - p0);                            \
        float s1 = p1 * p1 * __log2f(1.0f - p1);                            \
        float s2 = p2 * p2 * __log2f(1.0f - p2);                            \
        float s3 = p3 * p3 * __log2f(1.0f - p3);                            \
        acc += kk * ((s0 + s1) + (s2 + s3));                                \
        if ((unsigned)(lab - c0) < 4u) {                                    \
            int j = lab - c0;                                               \
            float p = (j == 0) ? p0 : (j == 1) ? p1 : (j == 2) ? p2 : p3;   \
            float q = 1.0f - p;                                             \
            acc += 0.69314718056f * (0.75f * p * p * __log2f(q)             \
                                   - 0.25f * q * q * __log2f(p));           \
        }                                                                   \
    }

    PROC(0, pr0) PROC(1, pr1) PROC(2, pr2) PROC(3, pr3) PROC(4, pr4)
    PROC(5, pr5) PROC(6, pr6) PROC(7, pr7) PROC(8, pr8) PROC(9, pr9)

    // 2-deep software pipeline over the remaining 10 chunks (10..19)
    {
        float4 c0v = base[PF * 256 + tid];
        float4 c1v = base[(PF + 1) * 256 + tid];
        #pragma unroll
        for (int i = PF; i < CHUNKS - 2; i += 2) {
            float4 n0 = base[(i + 2) * 256 + tid];
            float4 n1 = base[(i + 3) * 256 + tid];
            PROC(i, c0v)
            PROC(i + 1, c1v)
            c0v = n0; c1v = n1;
        }
        PROC(CHUNKS - 2, c0v)
        PROC(CHUNKS - 1, c1v)
    }
#undef PROC

    // ---- block reduction -> per-block slot (no atomics, no memset) ----
    #pragma unroll
    for (int off = 32; off > 0; off >>= 1)
        acc += __shfl_down(acc, off, 64);
    if (lane == 0) waveSums[wid] = acc;
    __syncthreads();
    if (tid == 0) {
        partial[bIdx] = waveSums[0] + waveSums[1] + waveSums[2] + waveSums[3];
        posCnt[bIdx]  = wavePos[0] + wavePos[1] + wavePos[2] + wavePos[3];
    }
}

__global__ __launch_bounds__(512) void focal_final(
    const float* __restrict__ partial,
    const int* __restrict__ posCnt,
    float* __restrict__ out)
{
    __shared__ float lossS[8];
    const int tid  = threadIdx.x;
    const int w    = tid >> 6;     // wave w handles sample b = w
    const int lane = tid & 63;

    float s = 0.0f;
    int   np = 0;
    #pragma unroll
    for (int k = 0; k < 4; ++k) {
        int i = w * 256 + lane + 64 * k;
        s  += partial[i];
        np += posCnt[i];
    }
    #pragma unroll
    for (int off = 32; off > 0; off >>= 1) {
        s  += __shfl_down(s, off, 64);
        np += __shfl_down(np, off, 64);
    }
    if (lane == 0) lossS[w] = s / fmaxf((float)np, 1.0f);
    __syncthreads();
    if (tid == 0) {
        float m = 0.0f;
        #pragma unroll
        for (int bb = 0; bb < BB; ++bb) m += lossS[bb];
        out[0] = m * (1.0f / BB);
    }
}

extern "C" void kernel_launch(void* const* d_in, const int* in_sizes, int n_in,
                              void* d_out, int out_size, void* d_ws, size_t ws_size,
                              hipStream_t stream) {
    const float* cls     = (const float*)d_in[0];
    const float* anchors = (const float*)d_in[1];
    const float* ann     = (const float*)d_in[2];
    float* out = (float*)d_out;

    float* partial = (float*)d_ws;                               // 2048 floats
    int*   posCnt  = (int*)((char*)d_ws + 2048 * sizeof(float)); // 2048 ints

    dim3 grid(GX, BB);
    focal_main<<<grid, 256, 0, stream>>>(cls, anchors, ann, partial, posCnt);
    focal_final<<<1, 512, 0, stream>>>(partial, posCnt, out);
}